// Round 9
// baseline (372.638 us; speedup 1.0000x reference)
//
#include <hip/hip_runtime.h>

// ---- problem constants ----
#define T_SEQ 2048
#define NB    2
#define NHEAD 16
#define NKV   4
#define HD    128
#define CDIM  2048
#define QKV_W 3072            // 2048 q + 512 k (+ 512 v, routed to Vt instead)
#define MROWS 4096            // B*T

// 1/sqrt(128) * log2(e); applied to q in-register inside attn (with RoPE)
#define QSCALE 0.12752648137154393f

typedef unsigned int  uint;
typedef unsigned short ushort;

typedef __attribute__((ext_vector_type(8))) __bf16 bf16x8;
typedef __attribute__((ext_vector_type(4))) float  floatx4;

#if __has_builtin(__builtin_amdgcn_exp2f)
#define EXP2F(x) __builtin_amdgcn_exp2f(x)
#else
#define EXP2F(x) exp2f(x)
#endif

__device__ __forceinline__ uint bf16rne(float f) {
  uint u = __float_as_uint(f);
  u += 0x7fffu + ((u >> 16) & 1u);
  return u >> 16;
}
__device__ __forceinline__ float bflo(uint w) { return __uint_as_float(w << 16); }
__device__ __forceinline__ float bfhi(uint w) { return __uint_as_float(w & 0xffff0000u); }

__device__ __forceinline__ void block_bar() {
  __builtin_amdgcn_sched_barrier(0);
  __builtin_amdgcn_s_barrier();
  __builtin_amdgcn_sched_barrier(0);
}

// ---- merged fp32 -> bf16 cast for all 5 inputs (dest regions contiguous) ----
__global__ void cast_all(const float* __restrict__ x,  const float* __restrict__ wq,
                         const float* __restrict__ wk, const float* __restrict__ wv,
                         const float* __restrict__ wo, uint* __restrict__ out) {
  int i = blockIdx.x * 256 + threadIdx.x;      // grid exactly 36864 * 256
  const float2* src; int off;
  if (i < 4194304)      { src = (const float2*)x;  off = 0; }
  else if (i < 6291456) { src = (const float2*)wq; off = 4194304; }
  else if (i < 6815744) { src = (const float2*)wk; off = 6291456; }
  else if (i < 7340032) { src = (const float2*)wv; off = 6815744; }
  else                  { src = (const float2*)wo; off = 7340032; }
  float2 v = src[i - off];
  out[i] = bf16rne(v.x) | (bf16rne(v.y) << 16);
}

// ---- GEMM C[M,N] = A[M,K] * Bt[N,K]^T  (bf16 in, OutT out) ----
// r5-proven structure (unchanged): 128x128 tile, BK=64, FOUR waves, wave tile
// 64x64. Dbuf LDS 64 KB -> 2 blocks/CU. Counted vmcnt. XOR swizzle on the
// GLOBAL source, inverted on ds_read (0 conflicts measured).
__device__ __forceinline__ void store_elem(ushort* C, size_t idx, float v) { C[idx] = (ushort)bf16rne(v); }
__device__ __forceinline__ void store_elem(float*  C, size_t idx, float v) { C[idx] = v; }

template <typename OutT>
__global__ __launch_bounds__(256, 2) void gemm_bt(const ushort* __restrict__ A,
                                                  const ushort* __restrict__ Bt,
                                                  OutT* __restrict__ C,
                                                  int M, int N, int K,
                                                  int vcol0, ushort* __restrict__ vt) {
  __shared__ ushort smem[32768];   // 65536 B
  const int tid  = threadIdx.x;
  const int wave = tid >> 6, lane = tid & 63;
  const int quad = lane >> 4, l16 = lane & 15;
  const int wm = wave >> 1, wn = wave & 1;
  const int mBase = blockIdx.y << 7;
  const int nBase = blockIdx.x << 7;
  const int NKT = K >> 6;

  floatx4 acc[4][4];
#pragma unroll
  for (int i = 0; i < 4; ++i)
#pragma unroll
    for (int j = 0; j < 4; ++j)
#pragma unroll
      for (int r = 0; r < 4; ++r) acc[i][j][r] = 0.f;

  const int srow = tid >> 3;
  const int sc8  = ((tid & 7) ^ (srow & 7)) << 3;
  const ushort* gA = A  + (size_t)(mBase + srow) * K + sc8;
  const ushort* gB = Bt + (size_t)(nBase + srow) * K + sc8;
  ushort* ldsA = smem + (wave << 9);
  ushort* ldsB = smem + 16384 + (wave << 9);

#define STAGE(k0, bsel)                                                               \
  do {                                                                                \
    _Pragma("unroll")                                                                 \
    for (int it_ = 0; it_ < 4; ++it_)                                                 \
      __builtin_amdgcn_global_load_lds(                                               \
          (const __attribute__((address_space(1))) void*)(gA + (size_t)it_ * 32 * K + (k0)), \
          (__attribute__((address_space(3))) void*)(ldsA + (bsel) + it_ * 2048), 16, 0, 0);  \
    _Pragma("unroll")                                                                 \
    for (int it_ = 0; it_ < 4; ++it_)                                                 \
      __builtin_amdgcn_global_load_lds(                                               \
          (const __attribute__((address_space(1))) void*)(gB + (size_t)it_ * 32 * K + (k0)), \
          (__attribute__((address_space(3))) void*)(ldsB + (bsel) + it_ * 2048), 16, 0, 0);  \
  } while (0)

  const int aro = ((wm << 6) + l16) * 64;
  const int bro = 16384 + ((wn << 6) + l16) * 64;
  const int sw0 = ((quad       ^ (l16 & 7)) << 3);
  const int sw1 = (((quad + 4) ^ (l16 & 7)) << 3);

  STAGE(0, 0);
  STAGE(64, 8192);
  asm volatile("s_waitcnt vmcnt(8)" ::: "memory");
  block_bar();

  for (int t = 0; t < NKT; ++t) {
    const int bsel = (t & 1) << 13;
#pragma unroll
    for (int kk = 0; kk < 2; ++kk) {
      const int sw = kk ? sw1 : sw0;
      bf16x8 bfrag[4];
#pragma unroll
      for (int j = 0; j < 4; ++j)
        bfrag[j] = *(const bf16x8*)&smem[bro + bsel + j * 1024 + sw];
#pragma unroll
      for (int i = 0; i < 4; ++i) {
        bf16x8 ai = *(const bf16x8*)&smem[aro + bsel + i * 1024 + sw];
#pragma unroll
        for (int j = 0; j < 4; ++j)
          acc[i][j] = __builtin_amdgcn_mfma_f32_16x16x32_bf16(ai, bfrag[j], acc[i][j], 0, 0, 0);
      }
    }
    asm volatile("s_waitcnt lgkmcnt(0)" ::: "memory");
    block_bar();
    if (t + 2 < NKT) {
      STAGE((t + 2) << 6, bsel);
      asm volatile("s_waitcnt vmcnt(8)" ::: "memory");
      block_bar();
    } else if (t + 1 < NKT) {
      asm volatile("s_waitcnt vmcnt(0)" ::: "memory");
      block_bar();
    }
  }
#undef STAGE

#pragma unroll
  for (int i = 0; i < 4; ++i) {
    const int rowb = mBase + (wm << 6) + (i << 4) + (quad << 2);
#pragma unroll
    for (int j = 0; j < 4; ++j) {
      const int colb = nBase + (wn << 6) + (j << 4);
      const int col  = colb + l16;
      if (colb < vcol0) {
#pragma unroll
        for (int r = 0; r < 4; ++r)
          store_elem(C, (size_t)(rowb + r) * N + col, acc[i][j][r]);
      } else {
        const int vcol = col - vcol0;
        const int bb = rowb >> 11;
        const int t  = rowb & 2047;
        uint2 pw;
        pw.x = bf16rne(acc[i][j][0]) | (bf16rne(acc[i][j][1]) << 16);
        pw.y = bf16rne(acc[i][j][2]) | (bf16rne(acc[i][j][3]) << 16);
        *(uint2*)(vt + (((size_t)(bb << 9) + vcol) << 11) + t) = pw;
      }
    }
  }
}

// ---- RoPE in-place on K columns only (q is roped in-register inside attn) ----
__global__ void rope_k(ushort* __restrict__ qkv, const float* __restrict__ fc,
                       const float* __restrict__ fs) {
  int idx  = blockIdx.x * 256 + threadIdx.x;   // exactly B*T*4*64 threads
  int d2   = idx & 63;
  int rest = idx >> 6;
  int hh   = rest & 3;
  int bt   = rest >> 2;
  int t    = bt & (T_SEQ - 1);
  float c = fc[(t << 6) + d2];
  float s = fs[(t << 6) + d2];
  uint* p = (uint*)(qkv + (size_t)bt * QKV_W + 2048 + (hh << 7) + (d2 << 1));
  uint w = *p;
  float e = bflo(w), o = bfhi(w);
  *p = bf16rne(e * c - o * s) | (bf16rne(e * s + o * c) << 16);
}

// ---- MFMA flash attention: Q-tile 128, key tile 64, EIGHT waves (512 thr) ----
// r9: LDS shrunk to 81,920 B (sP compact [128][64] with c4-XOR swizzle +
// two-pass epilogue) -> TWO blocks/CU co-resident. Grid 512 single-Q-tile
// blocks, heavy-first (xt = 15 - blockIdx.x) for dynamic load balance.
// Per-wave structure unchanged from r8 (wave-private P, one barrier/chunk,
// direct global_load_lds staging, in-register Q-RoPE).
__global__ __launch_bounds__(512, 4) void attn_mfma(const ushort* __restrict__ qkv,
                                                    const ushort* __restrict__ vtg,
                                                    ushort* __restrict__ y,
                                                    const float* __restrict__ fc,
                                                    const float* __restrict__ fs) {
  __shared__ ushort smem[40960];          // 81,920 B = 2 blocks/CU exactly
  // main : sK dbuf [2][64][128] @0/16KB | sVt dbuf [2][128][64] @32/48KB
  //        sP [128][64] @64KB (c4-XOR swizzled)                (ends 80KB)
  // epi  : per-tt pass overlay: sOf f32 [64][132] @0 (33.8KB) |
  //        sO ush [64][136] @33.8KB | sLf f32 [64] @51.2KB
  ushort* sP  = smem + 32768;
  float*  sOf = (float*)smem;
  ushort* sO  = smem + 16896;
  float*  sLf = (float*)(smem + 25600);

  const int tid  = threadIdx.x;
  const int wave = tid >> 6, lane = tid & 63;
  const int quad = lane >> 4, l16 = lane & 15;
  const int w_s = wave & 1;               // s-block owner (QK rows + PV k-slice)
  const int w_t = wave >> 1;              // t-block (0..3)
  const int h = blockIdx.y, b = blockIdx.z, kh = h >> 2;
  const size_t bT = (size_t)b * T_SEQ;

  union { uint4 u; bf16x8 v; } ones_u;
  ones_u.u = make_uint4(0x3F803F80u, 0x3F803F80u, 0x3F803F80u, 0x3F803F80u);
  const bf16x8 onesf = ones_u.v;

  const int kr  = tid >> 4;
  const int kc8 = tid & 15;
  const ushort* gK = qkv + (bT + kr) * QKV_W + 2048 + kh * HD + ((kc8 ^ (kr & 7)) << 3);
  const int vd  = tid >> 3;
  const int vsc = tid & 7;
  const ushort* gV = vtg + (((size_t)(b << 9) + (kh << 7) + vd) << 11) + ((vsc ^ (vd & 7)) << 3);

#define STAGE_ATTN(cn, bo_)                                                            \
  do {                                                                                 \
    _Pragma("unroll")                                                                  \
    for (int it_ = 0; it_ < 2; ++it_)                                                  \
      __builtin_amdgcn_global_load_lds(                                                \
          (const __attribute__((address_space(1))) void*)(gK + ((size_t)(cn) * 64 + it_ * 32) * QKV_W), \
          (__attribute__((address_space(3))) void*)(smem + (bo_) + (wave << 9) + it_ * 4096), 16, 0, 0); \
    _Pragma("unroll")                                                                  \
    for (int it_ = 0; it_ < 2; ++it_)                                                  \
      __builtin_amdgcn_global_load_lds(                                                \
          (const __attribute__((address_space(1))) void*)(gV + ((size_t)it_ << 17) + (cn) * 64), \
          (__attribute__((address_space(3))) void*)(smem + 16384 + (bo_) + (wave << 9) + it_ * 4096), 16, 0, 0); \
  } while (0)

  const int xt = 15 - (int)blockIdx.x;    // heavy tiles dispatch first
  const int t0 = xt << 7;
  const int sblk = w_s << 5, tblk = w_t << 5;

  // Q fragments: load raw q, apply RoPE + QSCALE in-register (in-lane pairs)
  bf16x8 qf[2][4];
#pragma unroll
  for (int tt = 0; tt < 2; ++tt) {
    const int trow = t0 + tblk + tt * 16 + l16;
    const float* fcr = fc + (trow << 6);
    const float* fsr = fs + (trow << 6);
#pragma unroll
    for (int kk = 0; kk < 4; ++kk) {
      union { uint4 u; bf16x8 v; } qa;
      qa.u = *(const uint4*)(qkv + (bT + trow) * QKV_W + h * HD + kk * 32 + quad * 8);
      const int d2b = kk * 16 + quad * 4;
      uint* wp = (uint*)&qa.u;
#pragma unroll
      for (int m = 0; m < 4; ++m) {
        float c = fcr[d2b + m], s = fsr[d2b + m];
        float e = bflo(wp[m]), o = bfhi(wp[m]);
        float oe = (e * c - o * s) * QSCALE;
        float oo = (e * s + o * c) * QSCALE;
        wp[m] = bf16rne(oe) | (bf16rne(oo) << 16);
      }
      qf[tt][kk] = qa.v;
    }
  }

  floatx4 oacc[2][8];     // t-tile (2) x full d (8 x 16)
  floatx4 lacc[2];
#pragma unroll
  for (int tt = 0; tt < 2; ++tt) {
#pragma unroll
    for (int r = 0; r < 4; ++r) lacc[tt][r] = 0.f;
#pragma unroll
    for (int dt = 0; dt < 8; ++dt)
#pragma unroll
      for (int r = 0; r < 4; ++r) oacc[tt][dt][r] = 0.f;
  }

  const int nch = (t0 >> 6) + 2;

  STAGE_ATTN(0, 0);       // prologue: chunk 0 -> buf0 (drained by first sync)

  for (int ch = 0; ch < nch; ++ch) {
    __syncthreads();      // buf[ch&1] staged (vmcnt drained); prev reads done
    if (ch + 1 < nch) STAGE_ATTN(ch + 1, ((ch + 1) & 1) << 13);
    const int bo = (ch & 1) << 13;        // 0 / 8192
    const int s0 = ch << 6;

    const bool fullmask = (s0 + sblk) > (t0 + tblk + 31);
    if (!fullmask) {
      floatx4 accS[2][2];
#pragma unroll
      for (int st = 0; st < 2; ++st)
#pragma unroll
        for (int tt = 0; tt < 2; ++tt)
#pragma unroll
          for (int r = 0; r < 4; ++r) accS[st][tt][r] = 0.f;

#pragma unroll
      for (int kk = 0; kk < 4; ++kk) {
        bf16x8 kf0 = *(const bf16x8*)(smem + bo + (sblk + l16) * 128 +
                                      ((((kk << 2) + quad) ^ (l16 & 7)) << 3));
        bf16x8 kf1 = *(const bf16x8*)(smem + bo + (sblk + 16 + l16) * 128 +
                                      ((((kk << 2) + quad) ^ (l16 & 7)) << 3));
#pragma unroll
        for (int tt = 0; tt < 2; ++tt)
          accS[0][tt] = __builtin_amdgcn_mfma_f32_16x16x32_bf16(kf0, qf[tt][kk], accS[0][tt], 0, 0, 0);
#pragma unroll
        for (int tt = 0; tt < 2; ++tt)
          accS[1][tt] = __builtin_amdgcn_mfma_f32_16x16x32_bf16(kf1, qf[tt][kk], accS[1][tt], 0, 0, 0);
      }

      const bool diag = (s0 + sblk + 31) > (t0 + tblk);
#pragma unroll
      for (int st = 0; st < 2; ++st)
#pragma unroll
        for (int tt = 0; tt < 2; ++tt) {
          float p[4];
          if (diag) {
            const int sg = s0 + sblk + st * 16 + quad * 4;
            const int tg = t0 + tblk + tt * 16 + l16;
#pragma unroll
            for (int r = 0; r < 4; ++r)
              p[r] = (sg + r <= tg) ? EXP2F(accS[st][tt][r]) : 0.f;
          } else {
#pragma unroll
            for (int r = 0; r < 4; ++r) p[r] = EXP2F(accS[st][tt][r]);
          }
          uint2 pw;   // truncating bf16 pack (bias cancels in normalization)
          pw.x = (__float_as_uint(p[0]) >> 16) | (__float_as_uint(p[1]) & 0xFFFF0000u);
          pw.y = (__float_as_uint(p[2]) >> 16) | (__float_as_uint(p[3]) & 0xFFFF0000u);
          // sP [128][64], c4-XOR swizzle: c4 = 8*w_s + st*4 + quad, XOR even
          const int c4s = (((w_s << 3) + (st << 2) + quad) ^ ((l16 & 7) << 1)) << 2;
          *(uint2*)(sP + ((tblk + tt * 16 + l16) << 6) + c4s) = pw;
        }
      // no barrier: P is wave-private

      bf16x8 pf[2];
#pragma unroll
      for (int tt = 0; tt < 2; ++tt) {
        // read back with the same row-XOR: c4 = 8*w_s + 2*quad (16B = 2 units)
        const int c4r = (((w_s << 3) + (quad << 1)) ^ ((l16 & 7) << 1)) << 2;
        pf[tt] = *(const bf16x8*)(sP + ((tblk + tt * 16 + l16) << 6) + c4r);
        lacc[tt] = __builtin_amdgcn_mfma_f32_16x16x32_bf16(pf[tt], onesf, lacc[tt], 0, 0, 0);
      }
#pragma unroll
      for (int dt = 0; dt < 8; ++dt) {
        bf16x8 vf = *(const bf16x8*)(smem + 16384 + bo + (dt * 16 + l16) * 64 +
                                     ((((w_s << 2) + quad) ^ (l16 & 7)) << 3));
#pragma unroll
        for (int tt = 0; tt < 2; ++tt)
          oacc[tt][dt] = __builtin_amdgcn_mfma_f32_16x16x32_bf16(pf[tt], vf, oacc[tt][dt], 0, 0, 0);
      }
    }
  }

  // ---- epilogue: two passes over tt (overlay fits the 80 KB budget) ----
#pragma unroll
  for (int tt = 0; tt < 2; ++tt) {
    __syncthreads();      // previous pass stores / last chunk reads done
    const int v = (w_t << 4) + (quad << 2);        // 0..63 virtual row
    if (w_s == 0) {
#pragma unroll
      for (int dt = 0; dt < 8; ++dt)
#pragma unroll
        for (int r = 0; r < 4; ++r)
          sOf[(v + r) * 132 + dt * 16 + l16] = oacc[tt][dt][r];
      if (l16 == 0) {
#pragma unroll
        for (int r = 0; r < 4; ++r) sLf[v + r] = lacc[tt][r];
      }
    }
    __syncthreads();
    if (w_s == 1) {
      float linv[4];
#pragma unroll
      for (int r = 0; r < 4; ++r) linv[r] = 1.0f / (sLf[v + r] + lacc[tt][r]);
#pragma unroll
      for (int dt = 0; dt < 8; ++dt)
#pragma unroll
        for (int r = 0; r < 4; ++r) {
          float val = (sOf[(v + r) * 132 + dt * 16 + l16] + oacc[tt][dt][r]) * linv[r];
          sO[(v + r) * 136 + dt * 16 + l16] = (ushort)bf16rne(val);
        }
    }
    __syncthreads();
#pragma unroll
    for (int it = 0; it < 2; ++it) {
      int idx = it * 512 + tid;                // 0..1023 = 64 v-rows x 16 chunks
      int vv = idx >> 4, c8 = idx & 15;
      int rr = ((vv >> 4) << 5) + tt * 16 + (vv & 15);   // physical t-row
      *(uint4*)(y + (bT + t0 + rr) * CDIM + h * HD + c8 * 8) =
          *(const uint4*)(sO + vv * 136 + c8 * 8);
    }
  }
#undef STAGE_ATTN
}

extern "C" void kernel_launch(void* const* d_in, const int* in_sizes, int n_in,
                              void* d_out, int out_size, void* d_ws, size_t ws_size,
                              hipStream_t stream) {
  const float* x    = (const float*)d_in[0];
  const float* fcos = (const float*)d_in[1];
  const float* fsin = (const float*)d_in[2];
  const float* wq   = (const float*)d_in[3];
  const float* wk   = (const float*)d_in[4];
  const float* wv   = (const float*)d_in[5];
  const float* wo   = (const float*)d_in[6];
  float* out = (float*)d_out;

  // workspace carve (bf16 elems); yb aliases xb (xb dead after gemm1)
  ushort* ws    = (ushort*)d_ws;
  ushort* xb    = ws;                          // 4096*2048 = 8,388,608
  ushort* yb    = ws;                          // alias of xb
  ushort* wqkvb = ws    + 8388608;             // 3072*2048 = 6,291,456
  ushort* wob   = wqkvb + 6291456;             // 2048*2048 = 4,194,304
  ushort* qkv   = wob   + 4194304;             // 4096*3072 = 12,582,912 (v cols unused)
  ushort* vtg   = qkv   + 12582912;            // 2*512*2048 = 2,097,152

  // 1) single merged fp32 -> bf16 cast (xb | wqkvb(q,k,v) | wob contiguous)
  cast_all<<<36864, 256, 0, stream>>>(x, wq, wk, wv, wo, (uint*)ws);

  // 2) qkv = xb @ Wqkv^T (raw q/k, no rope); V cols (>=2560) transposed to vtg
  gemm_bt<ushort><<<dim3(QKV_W / 128, MROWS / 128), 256, 0, stream>>>(
      xb, wqkvb, qkv, MROWS, QKV_W, CDIM, 2560, vtg);

  // 3) RoPE in place on K only (q is roped in-register inside attn)
  rope_k<<<4096, 256, 0, stream>>>(qkv, fcos, fsin);

  // 4) MFMA causal GQA attention -> yb: 512 single-tile blocks, 2 blocks/CU
  attn_mfma<<<dim3(16, NHEAD, NB), 512, 0, stream>>>(qkv, vtg, yb, fcos, fsin);

  // 5) out = yb @ wo^T (fp32 out)
  gemm_bt<float><<<dim3(CDIM / 128, MROWS / 128), 256, 0, stream>>>(
      yb, wob, out, MROWS, CDIM, CDIM, 1 << 30, nullptr);
}

// Round 10
// 274.089 us; speedup vs baseline: 1.3595x; 1.3595x over previous
//
#include <hip/hip_runtime.h>

// ---- problem constants ----
#define T_SEQ 2048
#define NB    2
#define NHEAD 16
#define NKV   4
#define HD    128
#define CDIM  2048
#define QKV_W 3072            // 2048 q + 512 k (+ 512 v, routed to Vt instead)
#define MROWS 4096            // B*T

// 1/sqrt(128) * log2(e); applied to q in-register inside attn (with RoPE)
#define QSCALE 0.12752648137154393f

typedef unsigned int  uint;
typedef unsigned short ushort;

typedef __attribute__((ext_vector_type(8))) __bf16 bf16x8;
typedef __attribute__((ext_vector_type(4))) float  floatx4;

#if __has_builtin(__builtin_amdgcn_exp2f)
#define EXP2F(x) __builtin_amdgcn_exp2f(x)
#else
#define EXP2F(x) exp2f(x)
#endif

__device__ __forceinline__ uint bf16rne(float f) {
  uint u = __float_as_uint(f);
  u += 0x7fffu + ((u >> 16) & 1u);
  return u >> 16;
}
__device__ __forceinline__ float bflo(uint w) { return __uint_as_float(w << 16); }
__device__ __forceinline__ float bfhi(uint w) { return __uint_as_float(w & 0xffff0000u); }

__device__ __forceinline__ void block_bar() {
  __builtin_amdgcn_sched_barrier(0);
  __builtin_amdgcn_s_barrier();
  __builtin_amdgcn_sched_barrier(0);
}

// ---- merged fp32 -> bf16 cast, float4 in / uint2 out (2 outputs/thread) ----
// ws layout (uint units): xb [0,4194304) | wq [4194304,6291456) |
// wk [6291456,6815744) | wv [6815744,7340032) | wo [7340032,9437184)
// All region boundaries are even in uint units -> no float4 straddles regions.
__global__ void cast_all(const float* __restrict__ x,  const float* __restrict__ wq,
                         const float* __restrict__ wk, const float* __restrict__ wv,
                         const float* __restrict__ wo, uint* __restrict__ out) {
  int i = blockIdx.x * 256 + threadIdx.x;      // grid exactly 18432 * 256
  int u0 = i << 1;                             // first uint index of this pair
  const float4* src; int off;                  // off in uint units
  if (u0 < 4194304)      { src = (const float4*)x;  off = 0; }
  else if (u0 < 6291456) { src = (const float4*)wq; off = 4194304; }
  else if (u0 < 6815744) { src = (const float4*)wk; off = 6291456; }
  else if (u0 < 7340032) { src = (const float4*)wv; off = 6815744; }
  else                   { src = (const float4*)wo; off = 7340032; }
  float4 v = src[(u0 - off) >> 1];
  uint2 o;
  o.x = bf16rne(v.x) | (bf16rne(v.y) << 16);
  o.y = bf16rne(v.z) | (bf16rne(v.w) << 16);
  *(uint2*)(out + u0) = o;
}

// ---- GEMM C[M,N] = A[M,K] * Bt[N,K]^T  (bf16 in, OutT out) ----
// r5-proven structure (unchanged): 128x128 tile, BK=64, FOUR waves, wave tile
// 64x64. Dbuf LDS 64 KB -> 2 blocks/CU. Counted vmcnt. XOR swizzle on the
// GLOBAL source, inverted on ds_read (0 conflicts measured).
__device__ __forceinline__ void store_elem(ushort* C, size_t idx, float v) { C[idx] = (ushort)bf16rne(v); }
__device__ __forceinline__ void store_elem(float*  C, size_t idx, float v) { C[idx] = v; }

template <typename OutT>
__global__ __launch_bounds__(256, 2) void gemm_bt(const ushort* __restrict__ A,
                                                  const ushort* __restrict__ Bt,
                                                  OutT* __restrict__ C,
                                                  int M, int N, int K,
                                                  int vcol0, ushort* __restrict__ vt) {
  __shared__ ushort smem[32768];   // 65536 B
  const int tid  = threadIdx.x;
  const int wave = tid >> 6, lane = tid & 63;
  const int quad = lane >> 4, l16 = lane & 15;
  const int wm = wave >> 1, wn = wave & 1;
  const int mBase = blockIdx.y << 7;
  const int nBase = blockIdx.x << 7;
  const int NKT = K >> 6;

  floatx4 acc[4][4];
#pragma unroll
  for (int i = 0; i < 4; ++i)
#pragma unroll
    for (int j = 0; j < 4; ++j)
#pragma unroll
      for (int r = 0; r < 4; ++r) acc[i][j][r] = 0.f;

  const int srow = tid >> 3;
  const int sc8  = ((tid & 7) ^ (srow & 7)) << 3;
  const ushort* gA = A  + (size_t)(mBase + srow) * K + sc8;
  const ushort* gB = Bt + (size_t)(nBase + srow) * K + sc8;
  ushort* ldsA = smem + (wave << 9);
  ushort* ldsB = smem + 16384 + (wave << 9);

#define STAGE(k0, bsel)                                                               \
  do {                                                                                \
    _Pragma("unroll")                                                                 \
    for (int it_ = 0; it_ < 4; ++it_)                                                 \
      __builtin_amdgcn_global_load_lds(                                               \
          (const __attribute__((address_space(1))) void*)(gA + (size_t)it_ * 32 * K + (k0)), \
          (__attribute__((address_space(3))) void*)(ldsA + (bsel) + it_ * 2048), 16, 0, 0);  \
    _Pragma("unroll")                                                                 \
    for (int it_ = 0; it_ < 4; ++it_)                                                 \
      __builtin_amdgcn_global_load_lds(                                               \
          (const __attribute__((address_space(1))) void*)(gB + (size_t)it_ * 32 * K + (k0)), \
          (__attribute__((address_space(3))) void*)(ldsB + (bsel) + it_ * 2048), 16, 0, 0);  \
  } while (0)

  const int aro = ((wm << 6) + l16) * 64;
  const int bro = 16384 + ((wn << 6) + l16) * 64;
  const int sw0 = ((quad       ^ (l16 & 7)) << 3);
  const int sw1 = (((quad + 4) ^ (l16 & 7)) << 3);

  STAGE(0, 0);
  STAGE(64, 8192);
  asm volatile("s_waitcnt vmcnt(8)" ::: "memory");
  block_bar();

  for (int t = 0; t < NKT; ++t) {
    const int bsel = (t & 1) << 13;
#pragma unroll
    for (int kk = 0; kk < 2; ++kk) {
      const int sw = kk ? sw1 : sw0;
      bf16x8 bfrag[4];
#pragma unroll
      for (int j = 0; j < 4; ++j)
        bfrag[j] = *(const bf16x8*)&smem[bro + bsel + j * 1024 + sw];
#pragma unroll
      for (int i = 0; i < 4; ++i) {
        bf16x8 ai = *(const bf16x8*)&smem[aro + bsel + i * 1024 + sw];
#pragma unroll
        for (int j = 0; j < 4; ++j)
          acc[i][j] = __builtin_amdgcn_mfma_f32_16x16x32_bf16(ai, bfrag[j], acc[i][j], 0, 0, 0);
      }
    }
    asm volatile("s_waitcnt lgkmcnt(0)" ::: "memory");
    block_bar();
    if (t + 2 < NKT) {
      STAGE((t + 2) << 6, bsel);
      asm volatile("s_waitcnt vmcnt(8)" ::: "memory");
      block_bar();
    } else if (t + 1 < NKT) {
      asm volatile("s_waitcnt vmcnt(0)" ::: "memory");
      block_bar();
    }
  }
#undef STAGE

#pragma unroll
  for (int i = 0; i < 4; ++i) {
    const int rowb = mBase + (wm << 6) + (i << 4) + (quad << 2);
#pragma unroll
    for (int j = 0; j < 4; ++j) {
      const int colb = nBase + (wn << 6) + (j << 4);
      const int col  = colb + l16;
      if (colb < vcol0) {
#pragma unroll
        for (int r = 0; r < 4; ++r)
          store_elem(C, (size_t)(rowb + r) * N + col, acc[i][j][r]);
      } else {
        const int vcol = col - vcol0;
        const int bb = rowb >> 11;
        const int t  = rowb & 2047;
        uint2 pw;
        pw.x = bf16rne(acc[i][j][0]) | (bf16rne(acc[i][j][1]) << 16);
        pw.y = bf16rne(acc[i][j][2]) | (bf16rne(acc[i][j][3]) << 16);
        *(uint2*)(vt + (((size_t)(bb << 9) + vcol) << 11) + t) = pw;
      }
    }
  }
}

// ---- RoPE in-place on K columns only (q is roped in-register inside attn) ----
__global__ void rope_k(ushort* __restrict__ qkv, const float* __restrict__ fc,
                       const float* __restrict__ fs) {
  int idx  = blockIdx.x * 256 + threadIdx.x;   // exactly B*T*4*64 threads
  int d2   = idx & 63;
  int rest = idx >> 6;
  int hh   = rest & 3;
  int bt   = rest >> 2;
  int t    = bt & (T_SEQ - 1);
  float c = fc[(t << 6) + d2];
  float s = fs[(t << 6) + d2];
  uint* p = (uint*)(qkv + (size_t)bt * QKV_W + 2048 + (hh << 7) + (d2 << 1));
  uint w = *p;
  float e = bflo(w), o = bfhi(w);
  *p = bf16rne(e * c - o * s) | (bf16rne(e * s + o * c) << 16);
}

// ---- MFMA flash attention: Q-tile 128, key tile 64, EIGHT waves (512 thr) ----
// r8-proven configuration (VERBATIM revert from r9's failed 2-block variant:
// per-wave live state ~100 VGPR is incompatible with (512,4) -> spill cliff).
// Grid 256 blocks (1/CU), blocks paired over Q-tiles {x, 15-x}: 34 chunks each.
// Wave-private P + dbuf direct global_load_lds staging -> ONE barrier per chunk.
// Q-RoPE + QSCALE applied in-register at qf load (in-lane pairs, no shfl).
__global__ __launch_bounds__(512, 2) void attn_mfma(const ushort* __restrict__ qkv,
                                                    const ushort* __restrict__ vtg,
                                                    ushort* __restrict__ y,
                                                    const float* __restrict__ fc,
                                                    const float* __restrict__ fs) {
  __shared__ ushort smem[51456];          // 102912 B
  ushort* sP = smem + 32768;
  float*  sOf = (float*)smem;
  ushort* sO  = smem + 33792;
  float*  sLf = (float*)(smem + 51200);

  const int tid  = threadIdx.x;
  const int wave = tid >> 6, lane = tid & 63;
  const int quad = lane >> 4, l16 = lane & 15;
  const int w_s = wave & 1;               // s-block owner (QK rows + PV k-slice)
  const int w_t = wave >> 1;              // t-block (0..3)
  const int h = blockIdx.y, b = blockIdx.z, kh = h >> 2;
  const size_t bT = (size_t)b * T_SEQ;

  union { uint4 u; bf16x8 v; } ones_u;
  ones_u.u = make_uint4(0x3F803F80u, 0x3F803F80u, 0x3F803F80u, 0x3F803F80u);
  const bf16x8 onesf = ones_u.v;

  const int kr  = tid >> 4;
  const int kc8 = tid & 15;
  const ushort* gK = qkv + (bT + kr) * QKV_W + 2048 + kh * HD + ((kc8 ^ (kr & 7)) << 3);
  const int vd  = tid >> 3;
  const int vsc = tid & 7;
  const ushort* gV = vtg + (((size_t)(b << 9) + (kh << 7) + vd) << 11) + ((vsc ^ (vd & 7)) << 3);

#define STAGE_ATTN(cn, bo_)                                                            \
  do {                                                                                 \
    _Pragma("unroll")                                                                  \
    for (int it_ = 0; it_ < 2; ++it_)                                                  \
      __builtin_amdgcn_global_load_lds(                                                \
          (const __attribute__((address_space(1))) void*)(gK + ((size_t)(cn) * 64 + it_ * 32) * QKV_W), \
          (__attribute__((address_space(3))) void*)(smem + (bo_) + (wave << 9) + it_ * 4096), 16, 0, 0); \
    _Pragma("unroll")                                                                  \
    for (int it_ = 0; it_ < 2; ++it_)                                                  \
      __builtin_amdgcn_global_load_lds(                                                \
          (const __attribute__((address_space(1))) void*)(gV + ((size_t)it_ << 17) + (cn) * 64), \
          (__attribute__((address_space(3))) void*)(smem + 16384 + (bo_) + (wave << 9) + it_ * 4096), 16, 0, 0); \
  } while (0)

  for (int half = 0; half < 2; ++half) {
    const int xt = half ? (15 - (int)blockIdx.x) : (int)blockIdx.x;
    const int t0 = xt << 7;
    const int sblk = w_s << 5, tblk = w_t << 5;

    // Q fragments: load raw q, apply RoPE + QSCALE in-register (in-lane pairs)
    bf16x8 qf[2][4];
#pragma unroll
    for (int tt = 0; tt < 2; ++tt) {
      const int trow = t0 + tblk + tt * 16 + l16;
      const float* fcr = fc + (trow << 6);
      const float* fsr = fs + (trow << 6);
#pragma unroll
      for (int kk = 0; kk < 4; ++kk) {
        union { uint4 u; bf16x8 v; } qa;
        qa.u = *(const uint4*)(qkv + (bT + trow) * QKV_W + h * HD + kk * 32 + quad * 8);
        const int d2b = kk * 16 + quad * 4;
        uint* wp = (uint*)&qa.u;
#pragma unroll
        for (int m = 0; m < 4; ++m) {
          float c = fcr[d2b + m], s = fsr[d2b + m];
          float e = bflo(wp[m]), o = bfhi(wp[m]);
          float oe = (e * c - o * s) * QSCALE;
          float oo = (e * s + o * c) * QSCALE;
          wp[m] = bf16rne(oe) | (bf16rne(oo) << 16);
        }
        qf[tt][kk] = qa.v;
      }
    }

    floatx4 oacc[2][8];     // t-tile (2) x full d (8 x 16)
    floatx4 lacc[2];
#pragma unroll
    for (int tt = 0; tt < 2; ++tt) {
#pragma unroll
      for (int r = 0; r < 4; ++r) lacc[tt][r] = 0.f;
#pragma unroll
      for (int dt = 0; dt < 8; ++dt)
#pragma unroll
        for (int r = 0; r < 4; ++r) oacc[tt][dt][r] = 0.f;
    }

    const int nch = (t0 >> 6) + 2;

    STAGE_ATTN(0, 0);       // prologue: chunk 0 -> buf0 (drained by first sync)

    for (int ch = 0; ch < nch; ++ch) {
      __syncthreads();      // buf[ch&1] staged (vmcnt drained); prev reads done
      if (ch + 1 < nch) STAGE_ATTN(ch + 1, ((ch + 1) & 1) << 13);
      const int bo = (ch & 1) << 13;        // 0 / 8192
      const int s0 = ch << 6;

      const bool fullmask = (s0 + sblk) > (t0 + tblk + 31);
      if (!fullmask) {
        floatx4 accS[2][2];
#pragma unroll
        for (int st = 0; st < 2; ++st)
#pragma unroll
          for (int tt = 0; tt < 2; ++tt)
#pragma unroll
            for (int r = 0; r < 4; ++r) accS[st][tt][r] = 0.f;

#pragma unroll
        for (int kk = 0; kk < 4; ++kk) {
          bf16x8 kf0 = *(const bf16x8*)(smem + bo + (sblk + l16) * 128 +
                                        ((((kk << 2) + quad) ^ (l16 & 7)) << 3));
          bf16x8 kf1 = *(const bf16x8*)(smem + bo + (sblk + 16 + l16) * 128 +
                                        ((((kk << 2) + quad) ^ (l16 & 7)) << 3));
#pragma unroll
          for (int tt = 0; tt < 2; ++tt)
            accS[0][tt] = __builtin_amdgcn_mfma_f32_16x16x32_bf16(kf0, qf[tt][kk], accS[0][tt], 0, 0, 0);
#pragma unroll
          for (int tt = 0; tt < 2; ++tt)
            accS[1][tt] = __builtin_amdgcn_mfma_f32_16x16x32_bf16(kf1, qf[tt][kk], accS[1][tt], 0, 0, 0);
        }

        const bool diag = (s0 + sblk + 31) > (t0 + tblk);
#pragma unroll
        for (int st = 0; st < 2; ++st)
#pragma unroll
          for (int tt = 0; tt < 2; ++tt) {
            float p[4];
            if (diag) {
              const int sg = s0 + sblk + st * 16 + quad * 4;
              const int tg = t0 + tblk + tt * 16 + l16;
#pragma unroll
              for (int r = 0; r < 4; ++r)
                p[r] = (sg + r <= tg) ? EXP2F(accS[st][tt][r]) : 0.f;
            } else {
#pragma unroll
              for (int r = 0; r < 4; ++r) p[r] = EXP2F(accS[st][tt][r]);
            }
            uint2 pw;   // truncating bf16 pack (bias cancels in normalization)
            pw.x = (__float_as_uint(p[0]) >> 16) | (__float_as_uint(p[1]) & 0xFFFF0000u);
            pw.y = (__float_as_uint(p[2]) >> 16) | (__float_as_uint(p[3]) & 0xFFFF0000u);
            *(uint2*)(sP + (tblk + tt * 16 + l16) * 72 + sblk + st * 16 + quad * 4) = pw;
          }
        // no barrier: P is wave-private

        bf16x8 pf[2];
#pragma unroll
        for (int tt = 0; tt < 2; ++tt) {
          pf[tt] = *(const bf16x8*)(sP + (tblk + tt * 16 + l16) * 72 + sblk + (quad << 3));
          lacc[tt] = __builtin_amdgcn_mfma_f32_16x16x32_bf16(pf[tt], onesf, lacc[tt], 0, 0, 0);
        }
#pragma unroll
        for (int dt = 0; dt < 8; ++dt) {
          bf16x8 vf = *(const bf16x8*)(smem + 16384 + bo + (dt * 16 + l16) * 64 +
                                       ((((w_s << 2) + quad) ^ (l16 & 7)) << 3));
#pragma unroll
          for (int tt = 0; tt < 2; ++tt)
            oacc[tt][dt] = __builtin_amdgcn_mfma_f32_16x16x32_bf16(pf[tt], vf, oacc[tt][dt], 0, 0, 0);
        }
      }
    }

    // ---- epilogue: combine w_s partials, normalize, coalesced store ----
    __syncthreads();
    if (w_s == 0) {
#pragma unroll
      for (int tt = 0; tt < 2; ++tt) {
#pragma unroll
        for (int dt = 0; dt < 8; ++dt)
#pragma unroll
          for (int r = 0; r < 4; ++r)
            sOf[(tblk + tt * 16 + quad * 4 + r) * 132 + dt * 16 + l16] = oacc[tt][dt][r];
        if (l16 == 0) {
#pragma unroll
          for (int r = 0; r < 4; ++r)
            sLf[tblk + tt * 16 + quad * 4 + r] = lacc[tt][r];
        }
      }
    }
    __syncthreads();
    if (w_s == 1) {
#pragma unroll
      for (int tt = 0; tt < 2; ++tt) {
        float linv[4];
#pragma unroll
        for (int r = 0; r < 4; ++r)
          linv[r] = 1.0f / (sLf[tblk + tt * 16 + quad * 4 + r] + lacc[tt][r]);
#pragma unroll
        for (int dt = 0; dt < 8; ++dt)
#pragma unroll
          for (int r = 0; r < 4; ++r) {
            float v = (sOf[(tblk + tt * 16 + quad * 4 + r) * 132 + dt * 16 + l16] +
                       oacc[tt][dt][r]) * linv[r];
            sO[(tblk + tt * 16 + quad * 4 + r) * 136 + dt * 16 + l16] = (ushort)bf16rne(v);
          }
      }
    }
    __syncthreads();
#pragma unroll
    for (int it = 0; it < 4; ++it) {
      int idx = it * 512 + tid;                  // 0..2047 = 128 rows x 16 chunks
      int rr = idx >> 4, c8 = idx & 15;
      *(uint4*)(y + (bT + t0 + rr) * CDIM + h * HD + c8 * 8) =
          *(const uint4*)(sO + rr * 136 + c8 * 8);
    }
  }
#undef STAGE_ATTN
}

extern "C" void kernel_launch(void* const* d_in, const int* in_sizes, int n_in,
                              void* d_out, int out_size, void* d_ws, size_t ws_size,
                              hipStream_t stream) {
  const float* x    = (const float*)d_in[0];
  const float* fcos = (const float*)d_in[1];
  const float* fsin = (const float*)d_in[2];
  const float* wq   = (const float*)d_in[3];
  const float* wk   = (const float*)d_in[4];
  const float* wv   = (const float*)d_in[5];
  const float* wo   = (const float*)d_in[6];
  float* out = (float*)d_out;

  // workspace carve (bf16 elems); yb aliases xb (xb dead after gemm1)
  ushort* ws    = (ushort*)d_ws;
  ushort* xb    = ws;                          // 4096*2048 = 8,388,608
  ushort* yb    = ws;                          // alias of xb
  ushort* wqkvb = ws    + 8388608;             // 3072*2048 = 6,291,456
  ushort* wob   = wqkvb + 6291456;             // 2048*2048 = 4,194,304
  ushort* qkv   = wob   + 4194304;             // 4096*3072 = 12,582,912 (v cols unused)
  ushort* vtg   = qkv   + 12582912;            // 2*512*2048 = 2,097,152

  // 1) single merged fp32 -> bf16 cast, float4/uint2 (2 outputs per thread)
  cast_all<<<18432, 256, 0, stream>>>(x, wq, wk, wv, wo, (uint*)ws);

  // 2) qkv = xb @ Wqkv^T (raw q/k, no rope); V cols (>=2560) transposed to vtg
  gemm_bt<ushort><<<dim3(QKV_W / 128, MROWS / 128), 256, 0, stream>>>(
      xb, wqkvb, qkv, MROWS, QKV_W, CDIM, 2560, vtg);

  // 3) RoPE in place on K only (q is roped in-register inside attn)
  rope_k<<<4096, 256, 0, stream>>>(qkv, fcos, fsin);

  // 4) MFMA causal GQA attention (r8-proven config) -> yb
  attn_mfma<<<dim3(8, NHEAD, NB), 512, 0, stream>>>(qkv, vtg, yb, fcos, fsin);

  // 5) out = yb @ wo^T (fp32 out)
  gemm_bt<float><<<dim3(CDIM / 128, MROWS / 128), 256, 0, stream>>>(
      yb, wob, out, MROWS, CDIM, CDIM, 1 << 30, nullptr);
}

// Round 11
// 272.901 us; speedup vs baseline: 1.3655x; 1.0044x over previous
//
#include <hip/hip_runtime.h>

// ---- problem constants ----
#define T_SEQ 2048
#define NB    2
#define NHEAD 16
#define NKV   4
#define HD    128
#define CDIM  2048
#define QKV_W 3072            // 2048 q + 512 k (+ 512 v, routed to Vt instead)
#define MROWS 4096            // B*T

// 1/sqrt(128) * log2(e); applied to q in-register inside attn (with RoPE)
#define QSCALE 0.12752648137154393f

typedef unsigned int  uint;
typedef unsigned short ushort;

typedef __attribute__((ext_vector_type(8))) __bf16 bf16x8;
typedef __attribute__((ext_vector_type(4))) float  floatx4;

#if __has_builtin(__builtin_amdgcn_exp2f)
#define EXP2F(x) __builtin_amdgcn_exp2f(x)
#else
#define EXP2F(x) exp2f(x)
#endif

__device__ __forceinline__ uint bf16rne(float f) {
  uint u = __float_as_uint(f);
  u += 0x7fffu + ((u >> 16) & 1u);
  return u >> 16;
}
__device__ __forceinline__ float bflo(uint w) { return __uint_as_float(w << 16); }
__device__ __forceinline__ float bfhi(uint w) { return __uint_as_float(w & 0xffff0000u); }

__device__ __forceinline__ void block_bar() {
  __builtin_amdgcn_sched_barrier(0);
  __builtin_amdgcn_s_barrier();
  __builtin_amdgcn_sched_barrier(0);
}

// ---- merged fp32 -> bf16 cast, float4 in / uint2 out (2 outputs/thread) ----
// ws layout (uint units): xb [0,4194304) | wq [4194304,6291456) |
// wk [6291456,6815744) | wv [6815744,7340032) | wo [7340032,9437184)
// All region boundaries are even in uint units -> no float4 straddles regions.
__global__ void cast_all(const float* __restrict__ x,  const float* __restrict__ wq,
                         const float* __restrict__ wk, const float* __restrict__ wv,
                         const float* __restrict__ wo, uint* __restrict__ out) {
  int i = blockIdx.x * 256 + threadIdx.x;      // grid exactly 18432 * 256
  int u0 = i << 1;                             // first uint index of this pair
  const float4* src; int off;                  // off in uint units
  if (u0 < 4194304)      { src = (const float4*)x;  off = 0; }
  else if (u0 < 6291456) { src = (const float4*)wq; off = 4194304; }
  else if (u0 < 6815744) { src = (const float4*)wk; off = 6291456; }
  else if (u0 < 7340032) { src = (const float4*)wv; off = 6815744; }
  else                   { src = (const float4*)wo; off = 7340032; }
  float4 v = src[(u0 - off) >> 1];
  uint2 o;
  o.x = bf16rne(v.x) | (bf16rne(v.y) << 16);
  o.y = bf16rne(v.z) | (bf16rne(v.w) << 16);
  *(uint2*)(out + u0) = o;
}

// ---- GEMM C[M,N] = A[M,K] * Bt[N,K]^T  (bf16 in, OutT out) ----
// r5-proven structure (unchanged): 128x128 tile, BK=64, FOUR waves, wave tile
// 64x64. Dbuf LDS 64 KB -> 2 blocks/CU. Counted vmcnt. XOR swizzle on the
// GLOBAL source, inverted on ds_read (0 conflicts measured).
__device__ __forceinline__ void store_elem(ushort* C, size_t idx, float v) { C[idx] = (ushort)bf16rne(v); }
__device__ __forceinline__ void store_elem(float*  C, size_t idx, float v) { C[idx] = v; }

template <typename OutT>
__global__ __launch_bounds__(256, 2) void gemm_bt(const ushort* __restrict__ A,
                                                  const ushort* __restrict__ Bt,
                                                  OutT* __restrict__ C,
                                                  int M, int N, int K,
                                                  int vcol0, ushort* __restrict__ vt) {
  __shared__ ushort smem[32768];   // 65536 B
  const int tid  = threadIdx.x;
  const int wave = tid >> 6, lane = tid & 63;
  const int quad = lane >> 4, l16 = lane & 15;
  const int wm = wave >> 1, wn = wave & 1;
  const int mBase = blockIdx.y << 7;
  const int nBase = blockIdx.x << 7;
  const int NKT = K >> 6;

  floatx4 acc[4][4];
#pragma unroll
  for (int i = 0; i < 4; ++i)
#pragma unroll
    for (int j = 0; j < 4; ++j)
#pragma unroll
      for (int r = 0; r < 4; ++r) acc[i][j][r] = 0.f;

  const int srow = tid >> 3;
  const int sc8  = ((tid & 7) ^ (srow & 7)) << 3;
  const ushort* gA = A  + (size_t)(mBase + srow) * K + sc8;
  const ushort* gB = Bt + (size_t)(nBase + srow) * K + sc8;
  ushort* ldsA = smem + (wave << 9);
  ushort* ldsB = smem + 16384 + (wave << 9);

#define STAGE(k0, bsel)                                                               \
  do {                                                                                \
    _Pragma("unroll")                                                                 \
    for (int it_ = 0; it_ < 4; ++it_)                                                 \
      __builtin_amdgcn_global_load_lds(                                               \
          (const __attribute__((address_space(1))) void*)(gA + (size_t)it_ * 32 * K + (k0)), \
          (__attribute__((address_space(3))) void*)(ldsA + (bsel) + it_ * 2048), 16, 0, 0);  \
    _Pragma("unroll")                                                                 \
    for (int it_ = 0; it_ < 4; ++it_)                                                 \
      __builtin_amdgcn_global_load_lds(                                               \
          (const __attribute__((address_space(1))) void*)(gB + (size_t)it_ * 32 * K + (k0)), \
          (__attribute__((address_space(3))) void*)(ldsB + (bsel) + it_ * 2048), 16, 0, 0);  \
  } while (0)

  const int aro = ((wm << 6) + l16) * 64;
  const int bro = 16384 + ((wn << 6) + l16) * 64;
  const int sw0 = ((quad       ^ (l16 & 7)) << 3);
  const int sw1 = (((quad + 4) ^ (l16 & 7)) << 3);

  STAGE(0, 0);
  STAGE(64, 8192);
  asm volatile("s_waitcnt vmcnt(8)" ::: "memory");
  block_bar();

  for (int t = 0; t < NKT; ++t) {
    const int bsel = (t & 1) << 13;
#pragma unroll
    for (int kk = 0; kk < 2; ++kk) {
      const int sw = kk ? sw1 : sw0;
      bf16x8 bfrag[4];
#pragma unroll
      for (int j = 0; j < 4; ++j)
        bfrag[j] = *(const bf16x8*)&smem[bro + bsel + j * 1024 + sw];
#pragma unroll
      for (int i = 0; i < 4; ++i) {
        bf16x8 ai = *(const bf16x8*)&smem[aro + bsel + i * 1024 + sw];
#pragma unroll
        for (int j = 0; j < 4; ++j)
          acc[i][j] = __builtin_amdgcn_mfma_f32_16x16x32_bf16(ai, bfrag[j], acc[i][j], 0, 0, 0);
      }
    }
    asm volatile("s_waitcnt lgkmcnt(0)" ::: "memory");
    block_bar();
    if (t + 2 < NKT) {
      STAGE((t + 2) << 6, bsel);
      asm volatile("s_waitcnt vmcnt(8)" ::: "memory");
      block_bar();
    } else if (t + 1 < NKT) {
      asm volatile("s_waitcnt vmcnt(0)" ::: "memory");
      block_bar();
    }
  }
#undef STAGE

#pragma unroll
  for (int i = 0; i < 4; ++i) {
    const int rowb = mBase + (wm << 6) + (i << 4) + (quad << 2);
#pragma unroll
    for (int j = 0; j < 4; ++j) {
      const int colb = nBase + (wn << 6) + (j << 4);
      const int col  = colb + l16;
      if (colb < vcol0) {
#pragma unroll
        for (int r = 0; r < 4; ++r)
          store_elem(C, (size_t)(rowb + r) * N + col, acc[i][j][r]);
      } else {
        const int vcol = col - vcol0;
        const int bb = rowb >> 11;
        const int t  = rowb & 2047;
        uint2 pw;
        pw.x = bf16rne(acc[i][j][0]) | (bf16rne(acc[i][j][1]) << 16);
        pw.y = bf16rne(acc[i][j][2]) | (bf16rne(acc[i][j][3]) << 16);
        *(uint2*)(vt + (((size_t)(bb << 9) + vcol) << 11) + t) = pw;
      }
    }
  }
}

// ---- RoPE in-place on K columns only (q is roped in-register inside attn) ----
__global__ void rope_k(ushort* __restrict__ qkv, const float* __restrict__ fc,
                       const float* __restrict__ fs) {
  int idx  = blockIdx.x * 256 + threadIdx.x;   // exactly B*T*4*64 threads
  int d2   = idx & 63;
  int rest = idx >> 6;
  int hh   = rest & 3;
  int bt   = rest >> 2;
  int t    = bt & (T_SEQ - 1);
  float c = fc[(t << 6) + d2];
  float s = fs[(t << 6) + d2];
  uint* p = (uint*)(qkv + (size_t)bt * QKV_W + 2048 + (hh << 7) + (d2 << 1));
  uint w = *p;
  float e = bflo(w), o = bfhi(w);
  *p = bf16rne(e * c - o * s) | (bf16rne(e * s + o * c) << 16);
}

// ---- MFMA flash attention: Q-tile 128, key tile 64, EIGHT waves (512 thr) ----
// r8-proven configuration + r11 micro-levers:
//  (a) s_setprio(1) around the QK and PV MFMA clusters (T5: waves here have
//      role diversity -- fullmask skips, wave-private P phases).
//  (b) staging pointers advanced incrementally per chunk (no per-chunk 64-bit
//      remultiplication of (cn*64)*QKV_W).
// Grid 256 blocks (1/CU), blocks paired over Q-tiles {x, 15-x}: 34 chunks each.
// Wave-private P + dbuf direct global_load_lds staging -> ONE barrier per chunk.
// Q-RoPE + QSCALE applied in-register at qf load (in-lane pairs, no shfl).
__global__ __launch_bounds__(512, 2) void attn_mfma(const ushort* __restrict__ qkv,
                                                    const ushort* __restrict__ vtg,
                                                    ushort* __restrict__ y,
                                                    const float* __restrict__ fc,
                                                    const float* __restrict__ fs) {
  __shared__ ushort smem[51456];          // 102912 B
  ushort* sP = smem + 32768;
  float*  sOf = (float*)smem;
  ushort* sO  = smem + 33792;
  float*  sLf = (float*)(smem + 51200);

  const int tid  = threadIdx.x;
  const int wave = tid >> 6, lane = tid & 63;
  const int quad = lane >> 4, l16 = lane & 15;
  const int w_s = wave & 1;               // s-block owner (QK rows + PV k-slice)
  const int w_t = wave >> 1;              // t-block (0..3)
  const int h = blockIdx.y, b = blockIdx.z, kh = h >> 2;
  const size_t bT = (size_t)b * T_SEQ;

  union { uint4 u; bf16x8 v; } ones_u;
  ones_u.u = make_uint4(0x3F803F80u, 0x3F803F80u, 0x3F803F80u, 0x3F803F80u);
  const bf16x8 onesf = ones_u.v;

  const int kr  = tid >> 4;
  const int kc8 = tid & 15;
  const ushort* gK = qkv + (bT + kr) * QKV_W + 2048 + kh * HD + ((kc8 ^ (kr & 7)) << 3);
  const int vd  = tid >> 3;
  const int vsc = tid & 7;
  const ushort* gV = vtg + (((size_t)(b << 9) + (kh << 7) + vd) << 11) + ((vsc ^ (vd & 7)) << 3);

#define STAGE_ATTN(kp_, vp_, bo_)                                                      \
  do {                                                                                 \
    _Pragma("unroll")                                                                  \
    for (int it_ = 0; it_ < 2; ++it_)                                                  \
      __builtin_amdgcn_global_load_lds(                                                \
          (const __attribute__((address_space(1))) void*)((kp_) + (size_t)it_ * 32 * QKV_W), \
          (__attribute__((address_space(3))) void*)(smem + (bo_) + (wave << 9) + it_ * 4096), 16, 0, 0); \
    _Pragma("unroll")                                                                  \
    for (int it_ = 0; it_ < 2; ++it_)                                                  \
      __builtin_amdgcn_global_load_lds(                                                \
          (const __attribute__((address_space(1))) void*)((vp_) + ((size_t)it_ << 17)), \
          (__attribute__((address_space(3))) void*)(smem + 16384 + (bo_) + (wave << 9) + it_ * 4096), 16, 0, 0); \
  } while (0)

  for (int half = 0; half < 2; ++half) {
    const int xt = half ? (15 - (int)blockIdx.x) : (int)blockIdx.x;
    const int t0 = xt << 7;
    const int sblk = w_s << 5, tblk = w_t << 5;

    // Q fragments: load raw q, apply RoPE + QSCALE in-register (in-lane pairs)
    bf16x8 qf[2][4];
#pragma unroll
    for (int tt = 0; tt < 2; ++tt) {
      const int trow = t0 + tblk + tt * 16 + l16;
      const float* fcr = fc + (trow << 6);
      const float* fsr = fs + (trow << 6);
#pragma unroll
      for (int kk = 0; kk < 4; ++kk) {
        union { uint4 u; bf16x8 v; } qa;
        qa.u = *(const uint4*)(qkv + (bT + trow) * QKV_W + h * HD + kk * 32 + quad * 8);
        const int d2b = kk * 16 + quad * 4;
        uint* wp = (uint*)&qa.u;
#pragma unroll
        for (int m = 0; m < 4; ++m) {
          float c = fcr[d2b + m], s = fsr[d2b + m];
          float e = bflo(wp[m]), o = bfhi(wp[m]);
          float oe = (e * c - o * s) * QSCALE;
          float oo = (e * s + o * c) * QSCALE;
          wp[m] = bf16rne(oe) | (bf16rne(oo) << 16);
        }
        qf[tt][kk] = qa.v;
      }
    }

    floatx4 oacc[2][8];     // t-tile (2) x full d (8 x 16)
    floatx4 lacc[2];
#pragma unroll
    for (int tt = 0; tt < 2; ++tt) {
#pragma unroll
      for (int r = 0; r < 4; ++r) lacc[tt][r] = 0.f;
#pragma unroll
      for (int dt = 0; dt < 8; ++dt)
#pragma unroll
        for (int r = 0; r < 4; ++r) oacc[tt][dt][r] = 0.f;
    }

    const int nch = (t0 >> 6) + 2;

    // incrementally-advanced staging pointers (chunk stride: K +64 rows, V +64 s)
    const ushort* kp = gK;
    const ushort* vp = gV;
    STAGE_ATTN(kp, vp, 0);  // prologue: chunk 0 -> buf0 (drained by first sync)

    for (int ch = 0; ch < nch; ++ch) {
      __syncthreads();      // buf[ch&1] staged (vmcnt drained); prev reads done
      if (ch + 1 < nch) {
        kp += (size_t)64 * QKV_W;
        vp += 64;
        STAGE_ATTN(kp, vp, ((ch + 1) & 1) << 13);
      }
      const int bo = (ch & 1) << 13;        // 0 / 8192
      const int s0 = ch << 6;

      const bool fullmask = (s0 + sblk) > (t0 + tblk + 31);
      if (!fullmask) {
        floatx4 accS[2][2];
#pragma unroll
        for (int st = 0; st < 2; ++st)
#pragma unroll
          for (int tt = 0; tt < 2; ++tt)
#pragma unroll
            for (int r = 0; r < 4; ++r) accS[st][tt][r] = 0.f;

        __builtin_amdgcn_s_setprio(1);
#pragma unroll
        for (int kk = 0; kk < 4; ++kk) {
          bf16x8 kf0 = *(const bf16x8*)(smem + bo + (sblk + l16) * 128 +
                                        ((((kk << 2) + quad) ^ (l16 & 7)) << 3));
          bf16x8 kf1 = *(const bf16x8*)(smem + bo + (sblk + 16 + l16) * 128 +
                                        ((((kk << 2) + quad) ^ (l16 & 7)) << 3));
#pragma unroll
          for (int tt = 0; tt < 2; ++tt)
            accS[0][tt] = __builtin_amdgcn_mfma_f32_16x16x32_bf16(kf0, qf[tt][kk], accS[0][tt], 0, 0, 0);
#pragma unroll
          for (int tt = 0; tt < 2; ++tt)
            accS[1][tt] = __builtin_amdgcn_mfma_f32_16x16x32_bf16(kf1, qf[tt][kk], accS[1][tt], 0, 0, 0);
        }
        __builtin_amdgcn_s_setprio(0);

        const bool diag = (s0 + sblk + 31) > (t0 + tblk);
#pragma unroll
        for (int st = 0; st < 2; ++st)
#pragma unroll
          for (int tt = 0; tt < 2; ++tt) {
            float p[4];
            if (diag) {
              const int sg = s0 + sblk + st * 16 + quad * 4;
              const int tg = t0 + tblk + tt * 16 + l16;
#pragma unroll
              for (int r = 0; r < 4; ++r)
                p[r] = (sg + r <= tg) ? EXP2F(accS[st][tt][r]) : 0.f;
            } else {
#pragma unroll
              for (int r = 0; r < 4; ++r) p[r] = EXP2F(accS[st][tt][r]);
            }
            uint2 pw;   // truncating bf16 pack (bias cancels in normalization)
            pw.x = (__float_as_uint(p[0]) >> 16) | (__float_as_uint(p[1]) & 0xFFFF0000u);
            pw.y = (__float_as_uint(p[2]) >> 16) | (__float_as_uint(p[3]) & 0xFFFF0000u);
            *(uint2*)(sP + (tblk + tt * 16 + l16) * 72 + sblk + st * 16 + quad * 4) = pw;
          }
        // no barrier: P is wave-private

        bf16x8 pf[2];
#pragma unroll
        for (int tt = 0; tt < 2; ++tt)
          pf[tt] = *(const bf16x8*)(sP + (tblk + tt * 16 + l16) * 72 + sblk + (quad << 3));
        __builtin_amdgcn_s_setprio(1);
#pragma unroll
        for (int tt = 0; tt < 2; ++tt)
          lacc[tt] = __builtin_amdgcn_mfma_f32_16x16x32_bf16(pf[tt], onesf, lacc[tt], 0, 0, 0);
#pragma unroll
        for (int dt = 0; dt < 8; ++dt) {
          bf16x8 vf = *(const bf16x8*)(smem + 16384 + bo + (dt * 16 + l16) * 64 +
                                       ((((w_s << 2) + quad) ^ (l16 & 7)) << 3));
#pragma unroll
          for (int tt = 0; tt < 2; ++tt)
            oacc[tt][dt] = __builtin_amdgcn_mfma_f32_16x16x32_bf16(pf[tt], vf, oacc[tt][dt], 0, 0, 0);
        }
        __builtin_amdgcn_s_setprio(0);
      }
    }

    // ---- epilogue: combine w_s partials, normalize, coalesced store ----
    __syncthreads();
    if (w_s == 0) {
#pragma unroll
      for (int tt = 0; tt < 2; ++tt) {
#pragma unroll
        for (int dt = 0; dt < 8; ++dt)
#pragma unroll
          for (int r = 0; r < 4; ++r)
            sOf[(tblk + tt * 16 + quad * 4 + r) * 132 + dt * 16 + l16] = oacc[tt][dt][r];
        if (l16 == 0) {
#pragma unroll
          for (int r = 0; r < 4; ++r)
            sLf[tblk + tt * 16 + quad * 4 + r] = lacc[tt][r];
        }
      }
    }
    __syncthreads();
    if (w_s == 1) {
#pragma unroll
      for (int tt = 0; tt < 2; ++tt) {
        float linv[4];
#pragma unroll
        for (int r = 0; r < 4; ++r)
          linv[r] = 1.0f / (sLf[tblk + tt * 16 + quad * 4 + r] + lacc[tt][r]);
#pragma unroll
        for (int dt = 0; dt < 8; ++dt)
#pragma unroll
          for (int r = 0; r < 4; ++r) {
            float v = (sOf[(tblk + tt * 16 + quad * 4 + r) * 132 + dt * 16 + l16] +
                       oacc[tt][dt][r]) * linv[r];
            sO[(tblk + tt * 16 + quad * 4 + r) * 136 + dt * 16 + l16] = (ushort)bf16rne(v);
          }
      }
    }
    __syncthreads();
#pragma unroll
    for (int it = 0; it < 4; ++it) {
      int idx = it * 512 + tid;                  // 0..2047 = 128 rows x 16 chunks
      int rr = idx >> 4, c8 = idx & 15;
      *(uint4*)(y + (bT + t0 + rr) * CDIM + h * HD + c8 * 8) =
          *(const uint4*)(sO + rr * 136 + c8 * 8);
    }
  }
#undef STAGE_ATTN
}

extern "C" void kernel_launch(void* const* d_in, const int* in_sizes, int n_in,
                              void* d_out, int out_size, void* d_ws, size_t ws_size,
                              hipStream_t stream) {
  const float* x    = (const float*)d_in[0];
  const float* fcos = (const float*)d_in[1];
  const float* fsin = (const float*)d_in[2];
  const float* wq   = (const float*)d_in[3];
  const float* wk   = (const float*)d_in[4];
  const float* wv   = (const float*)d_in[5];
  const float* wo   = (const float*)d_in[6];
  float* out = (float*)d_out;

  // workspace carve (bf16 elems); yb aliases xb (xb dead after gemm1)
  ushort* ws    = (ushort*)d_ws;
  ushort* xb    = ws;                          // 4096*2048 = 8,388,608
  ushort* yb    = ws;                          // alias of xb
  ushort* wqkvb = ws    + 8388608;             // 3072*2048 = 6,291,456
  ushort* wob   = wqkvb + 6291456;             // 2048*2048 = 4,194,304
  ushort* qkv   = wob   + 4194304;             // 4096*3072 = 12,582,912 (v cols unused)
  ushort* vtg   = qkv   + 12582912;            // 2*512*2048 = 2,097,152

  // 1) single merged fp32 -> bf16 cast, float4/uint2 (2 outputs per thread)
  cast_all<<<18432, 256, 0, stream>>>(x, wq, wk, wv, wo, (uint*)ws);

  // 2) qkv = xb @ Wqkv^T (raw q/k, no rope); V cols (>=2560) transposed to vtg
  gemm_bt<ushort><<<dim3(QKV_W / 128, MROWS / 128), 256, 0, stream>>>(
      xb, wqkvb, qkv, MROWS, QKV_W, CDIM, 2560, vtg);

  // 3) RoPE in place on K only (q is roped in-register inside attn)
  rope_k<<<4096, 256, 0, stream>>>(qkv, fcos, fsin);

  // 4) MFMA causal GQA attention (r8 config + setprio + incremental staging) -> yb
  attn_mfma<<<dim3(8, NHEAD, NB), 512, 0, stream>>>(qkv, vtg, yb, fcos, fsin);

  // 5) out = yb @ wo^T (fp32 out)
  gemm_bt<float><<<dim3(CDIM / 128, MROWS / 128), 256, 0, stream>>>(
      yb, wob, out, MROWS, CDIM, CDIM, 1 << 30, nullptr);
}